// Round 4
// baseline (1034.075 us; speedup 1.0000x reference)
//
#include <hip/hip_runtime.h>

// OnlineDenoisingAutoencoder: LSTM(B=2048, T=2048, in=1, proj=16, H=32)
// 1 wave per batch element (2048 waves = 2/SIMD). Lane l owns W_hh rows l and
// 64+l in registers. Input pipeline collapsed to gate = x*A + C (INPUT_DIM==1).
// R4: h broadcast via v_readlane -> SGPR (zero LDS). R2's 8x ds_read_b128/step
// saturated the per-CU LDS pipe (8 waves x ~142 cyc = 1136 cyc/step = measured
// step time). Dots are v_fma_f32 with SGPR h operand. Only LDS-pipe traffic
// left: 7 ds_swizzle/step (cross-half exchange + output reduce) -> not binding.
// R3 lesson: v_pk_fma_f32 is NOT double-rate fp32 on gfx950 — reverted.

#define BB 2048
#define TT 2048
#define HH 32

__device__ __forceinline__ float gate_eval(float x, float m, float a, float b) {
    // a * (1 / (1 + 2^(m*x))) + b ; sigmoid: m=-log2e,a=1,b=0 ; tanh: m=-2log2e,a=2,b=-1
    float e = __builtin_amdgcn_exp2f(x * m);
    float r = __builtin_amdgcn_rcpf(1.0f + e);
    return fmaf(a, r, b);
}

__device__ __forceinline__ float lane_bcast(float v, int k) {
    return __int_as_float(__builtin_amdgcn_readlane(__float_as_int(v), k));
}

__global__ __launch_bounds__(256) void lstm_fused_kernel(
    const float* __restrict__ x_seq,  // [B,T,1]
    const float* __restrict__ Wp,     // [16,1]
    const float* __restrict__ bp,     // [16]
    const float* __restrict__ W_ih,   // [128,16]
    const float* __restrict__ W_hh,   // [128,32]
    const float* __restrict__ b_ih,   // [128]
    const float* __restrict__ b_hh,   // [128]
    const float* __restrict__ Wo,     // [1,32]
    const float* __restrict__ bo,     // [1]
    float* __restrict__ out)          // [B,T,1] fp32
{
    const int tid  = threadIdx.x;
    const int wave = tid >> 6;
    const int lane = tid & 63;
    const int half = lane >> 5;      // 0: rows l (i), 64+l (g); 1: rows l (f), 64+l (o)
    const int j    = lane & 31;      // hidden index this lane owns
    const int b    = blockIdx.x * 4 + wave;

    const int rA = lane;             // rows 0..63  : i (l<32) / f (l>=32)
    const int rB = 64 + lane;        // rows 64..127: g (l<32) / o (l>=32)

    // ---- W_hh rows into registers (one-time) ----
    float wA[HH], wB[HH];
    {
        const float4* pa = (const float4*)(W_hh + rA * HH);
        const float4* pb = (const float4*)(W_hh + rB * HH);
#pragma unroll
        for (int k = 0; k < HH / 4; ++k) {
            float4 va = pa[k], vb = pb[k];
            wA[4*k+0] = va.x; wA[4*k+1] = va.y; wA[4*k+2] = va.z; wA[4*k+3] = va.w;
            wB[4*k+0] = vb.x; wB[4*k+1] = vb.y; wB[4*k+2] = vb.z; wB[4*k+3] = vb.w;
        }
    }

    // ---- collapse input pipeline: gate_g(x) = x*a + c ----
    float aA = 0.f, cA = 0.f, aB = 0.f, cB = 0.f;
#pragma unroll
    for (int p = 0; p < 16; ++p) {
        float wia = W_ih[rA * 16 + p], wib = W_ih[rB * 16 + p];
        aA = fmaf(wia, Wp[p], aA);
        cA = fmaf(wia, bp[p], cA);
        aB = fmaf(wib, Wp[p], aB);
        cB = fmaf(wib, bp[p], cB);
    }
    cA += b_ih[rA] + b_hh[rA];
    cB += b_ih[rB] + b_hh[rB];

    const float LOG2E = 1.44269504088896340736f;
    const float mB  = half ? -LOG2E : -2.0f * LOG2E;  // B-gate: tanh(g) | sigmoid(o)
    const float aBc = half ? 1.0f : 2.0f;
    const float bBc = half ? 0.0f : -1.0f;

    const float woj = Wo[j];
    const float bo0 = bo[0];

    float c = 0.0f;
    float h = 0.0f;   // lane's own h_j (duplicated across halves)
    const float* xp = x_seq + (size_t)b * TT;
    float* op = out + (size_t)b * TT;

    for (int t = 0; t < TT; t += 4) {
        float4 x4 = *(const float4*)(xp + t);
        float outv[4];
#pragma unroll
        for (int u = 0; u < 4; ++u) {
            float xv = (u == 0) ? x4.x : (u == 1) ? x4.y : (u == 2) ? x4.z : x4.w;

            // two 32-long dots; h broadcast lane->SGPR via readlane (no LDS).
            // even/odd accumulator split for ILP; v_fma_f32 takes the SGPR h.
            float sA0 = cA, sA1 = xv * aA;
            float sB0 = cB, sB1 = xv * aB;
#pragma unroll
            for (int k = 0; k < HH; k += 2) {
                float h0 = lane_bcast(h, k);
                float h1 = lane_bcast(h, k + 1);
                sA0 = fmaf(wA[k],     h0, sA0);
                sB0 = fmaf(wB[k],     h0, sB0);
                sA1 = fmaf(wA[k + 1], h1, sA1);
                sB1 = fmaf(wB[k + 1], h1, sB1);
            }
            float gA = sA0 + sA1;
            float gB = sB0 + sB1;

            float vA = gate_eval(gA, -LOG2E, 1.0f, 0.0f); // sigmoid(i or f)
            float vB = gate_eval(gB, mB, aBc, bBc);       // tanh(g) or sigmoid(o)

            // exchange across halves so both compute the cell update
            float pA = __shfl_xor(vA, 32, 64);
            float pB = __shfl_xor(vB, 32, 64);
            float iv = half ? pA : vA;
            float fv = half ? vA : pA;
            float gv = half ? pB : vB;
            float ov = half ? vB : pB;

            c = fmaf(fv, c, iv * gv);
            float th = gate_eval(c, -2.0f * LOG2E, 2.0f, -1.0f); // tanh(c)
            h = ov * th;

            // fused output projection: dot(Wo, h) via shuffle reduce (width 32)
            float po = woj * h;
#pragma unroll
            for (int m = 16; m >= 1; m >>= 1)
                po += __shfl_xor(po, m, 32);
            outv[u] = po + bo0;
        }
        if (lane == 0) {
            *(float4*)(op + t) = make_float4(outv[0], outv[1], outv[2], outv[3]);
        }
    }
}

extern "C" void kernel_launch(void* const* d_in, const int* in_sizes, int n_in,
                              void* d_out, int out_size, void* d_ws, size_t ws_size,
                              hipStream_t stream) {
    const float* x_seq = (const float*)d_in[0];
    const float* Wp    = (const float*)d_in[1];
    const float* bp    = (const float*)d_in[2];
    const float* W_ih  = (const float*)d_in[3];
    const float* W_hh  = (const float*)d_in[4];
    const float* b_ih  = (const float*)d_in[5];
    const float* b_hh  = (const float*)d_in[6];
    const float* Wo    = (const float*)d_in[7];
    const float* bo    = (const float*)d_in[8];
    float* out = (float*)d_out;

    dim3 grid(BB / 4);   // 4 waves per block, 1 batch element per wave
    dim3 block(256);
    lstm_fused_kernel<<<grid, block, 0, stream>>>(
        x_seq, Wp, bp, W_ih, W_hh, b_ih, b_hh, Wo, bo, out);
}

// Round 6
// 670.216 us; speedup vs baseline: 1.5429x; 1.5429x over previous
//
#include <hip/hip_runtime.h>

// OnlineDenoisingAutoencoder: LSTM(B=2048, T=2048, in=1, proj=16, H=32)
// R6 = R5 with the DPP ctrl as a template arg (builtin requires ICE).
// 2 batch elements per wave (half = batch, j = lane&31). Each lane computes
// ALL FOUR gates for its (b, j): no cross-half exchange, no duplicated trans,
// no selects. Dots use v_dot2_f32_f16 (full-rate, fp32 accum) with fp16 weights
// in registers; h stored fp16 in LDS (4 ds_read_b128/wave-step serves 2
// batches). c stays fp32 in-register -> fp16 only perturbs gate inputs.
// Output reduce on VALU via DPP (row_shr + row_bcast15), result in lane 31/63.
// x software-prefetched one 4-step group ahead. 1024 waves (1/SIMD).
// History: R2 LDS-pipe-bound 864us; R3 pk_fma NOT 2x on gfx950 (996us);
// R4 readlane broadcast costs ~2x modeled VALU (1034us).

#define BB 2048
#define TT 2048
#define HH 32

typedef _Float16 h2 __attribute__((ext_vector_type(2)));

__device__ __forceinline__ float gate_eval(float x, float m, float a, float b) {
    // a * (1 / (1 + 2^(m*x))) + b ; sigmoid: m=-log2e,a=1,b=0 ; tanh: m=-2log2e,a=2,b=-1
    float e = __builtin_amdgcn_exp2f(x * m);
    float r = __builtin_amdgcn_rcpf(1.0f + e);
    return fmaf(a, r, b);
}

template <int CTRL>
__device__ __forceinline__ float dpp_add(float v) {
    int s = __builtin_amdgcn_update_dpp(0, __float_as_int(v), CTRL, 0xf, 0xf, true);
    return v + __int_as_float(s);
}

struct HVec { h2 v[16]; };

__device__ __forceinline__ HVec gather_h(const _Float16* base) {
    const float4* p = (const float4*)base;   // 64 B = 4 x ds_read_b128 (broadcast)
    float4 q0 = p[0], q1 = p[1], q2 = p[2], q3 = p[3];
    HVec r;
    r.v[0]  = __builtin_bit_cast(h2, q0.x); r.v[1]  = __builtin_bit_cast(h2, q0.y);
    r.v[2]  = __builtin_bit_cast(h2, q0.z); r.v[3]  = __builtin_bit_cast(h2, q0.w);
    r.v[4]  = __builtin_bit_cast(h2, q1.x); r.v[5]  = __builtin_bit_cast(h2, q1.y);
    r.v[6]  = __builtin_bit_cast(h2, q1.z); r.v[7]  = __builtin_bit_cast(h2, q1.w);
    r.v[8]  = __builtin_bit_cast(h2, q2.x); r.v[9]  = __builtin_bit_cast(h2, q2.y);
    r.v[10] = __builtin_bit_cast(h2, q2.z); r.v[11] = __builtin_bit_cast(h2, q2.w);
    r.v[12] = __builtin_bit_cast(h2, q3.x); r.v[13] = __builtin_bit_cast(h2, q3.y);
    r.v[14] = __builtin_bit_cast(h2, q3.z); r.v[15] = __builtin_bit_cast(h2, q3.w);
    return r;
}

__global__ __launch_bounds__(256) void lstm_fused_kernel(
    const float* __restrict__ x_seq,  // [B,T,1]
    const float* __restrict__ Wp,     // [16,1]
    const float* __restrict__ bp,     // [16]
    const float* __restrict__ W_ih,   // [128,16]
    const float* __restrict__ W_hh,   // [128,32]
    const float* __restrict__ b_ih,   // [128]
    const float* __restrict__ b_hh,   // [128]
    const float* __restrict__ Wo,     // [1,32]
    const float* __restrict__ bo,     // [1]
    float* __restrict__ out)          // [B,T,1] fp32
{
    const int tid  = threadIdx.x;
    const int wave = tid >> 6;
    const int lane = tid & 63;
    const int half = lane >> 5;      // which of the wave's 2 batch elements
    const int j    = lane & 31;      // hidden index this lane owns
    const int b    = blockIdx.x * 8 + wave * 2 + half;

    // PyTorch gate row order: i=[0,32), f=[32,64), g=[64,96), o=[96,128)
    const int rI = j, rF = HH + j, rG = 2 * HH + j, rO = 3 * HH + j;

    // ---- W_hh rows (4 gates) into registers as packed fp16 pairs ----
    h2 wI[16], wF[16], wG[16], wO[16];
    {
        const float2* pI = (const float2*)(W_hh + rI * HH);
        const float2* pF = (const float2*)(W_hh + rF * HH);
        const float2* pG = (const float2*)(W_hh + rG * HH);
        const float2* pO = (const float2*)(W_hh + rO * HH);
#pragma unroll
        for (int k = 0; k < 16; ++k) {
            float2 a = pI[k], f = pF[k], g = pG[k], o = pO[k];
            wI[k].x = (_Float16)a.x; wI[k].y = (_Float16)a.y;
            wF[k].x = (_Float16)f.x; wF[k].y = (_Float16)f.y;
            wG[k].x = (_Float16)g.x; wG[k].y = (_Float16)g.y;
            wO[k].x = (_Float16)o.x; wO[k].y = (_Float16)o.y;
        }
    }

    // ---- collapse input pipeline: gate pre-act = dot + x*a + c (INPUT_DIM==1) ----
    float aI = 0.f, cI = 0.f, aF = 0.f, cF = 0.f;
    float aG = 0.f, cG = 0.f, aO = 0.f, cO = 0.f;
#pragma unroll
    for (int p = 0; p < 16; ++p) {
        float wpv = Wp[p], bpv = bp[p];
        float wi = W_ih[rI * 16 + p], wf = W_ih[rF * 16 + p];
        float wg = W_ih[rG * 16 + p], wo_ = W_ih[rO * 16 + p];
        aI = fmaf(wi, wpv, aI);  cI = fmaf(wi, bpv, cI);
        aF = fmaf(wf, wpv, aF);  cF = fmaf(wf, bpv, cF);
        aG = fmaf(wg, wpv, aG);  cG = fmaf(wg, bpv, cG);
        aO = fmaf(wo_, wpv, aO); cO = fmaf(wo_, bpv, cO);
    }
    cI += b_ih[rI] + b_hh[rI];
    cF += b_ih[rF] + b_hh[rF];
    cG += b_ih[rG] + b_hh[rG];
    cO += b_ih[rO] + b_hh[rO];

    const float LOG2E = 1.44269504088896340736f;
    const float woj = Wo[j];
    const float bo0 = bo[0];

    // per-(wave,batch) h buffer, fp16, 64 B each
    __shared__ __align__(16) _Float16 hsh[4][2][HH];
    _Float16* hbase = &hsh[wave][half][0];
    hbase[j] = (_Float16)0.0f;

    float c = 0.0f;
    const float* xp = x_seq + (size_t)b * TT;
    float* op = out + (size_t)b * TT;

    HVec hcur = gather_h(hbase);            // zeros (same-wave DS order)
    float4 x4 = *(const float4*)(xp);

    for (int t = 0; t < TT; t += 4) {
        const int tn = (t + 4 < TT) ? (t + 4) : t;
        float4 x4n = *(const float4*)(xp + tn);   // prefetch next group
        float outv[4];
#pragma unroll
        for (int u = 0; u < 4; ++u) {
            float xv = (u == 0) ? x4.x : (u == 1) ? x4.y : (u == 2) ? x4.z : x4.w;

            // 4 gate dots over h (fp16 inputs, fp32 accum), 2 accumulators each
            float sI0 = cI, sI1 = xv * aI;
            float sF0 = cF, sF1 = xv * aF;
            float sG0 = cG, sG1 = xv * aG;
            float sO0 = cO, sO1 = xv * aO;
#pragma unroll
            for (int k = 0; k < 16; k += 2) {
                h2 h0 = hcur.v[k], h1 = hcur.v[k + 1];
                sI0 = __builtin_amdgcn_fdot2(wI[k],     h0, sI0, false);
                sF0 = __builtin_amdgcn_fdot2(wF[k],     h0, sF0, false);
                sG0 = __builtin_amdgcn_fdot2(wG[k],     h0, sG0, false);
                sO0 = __builtin_amdgcn_fdot2(wO[k],     h0, sO0, false);
                sI1 = __builtin_amdgcn_fdot2(wI[k + 1], h1, sI1, false);
                sF1 = __builtin_amdgcn_fdot2(wF[k + 1], h1, sF1, false);
                sG1 = __builtin_amdgcn_fdot2(wG[k + 1], h1, sG1, false);
                sO1 = __builtin_amdgcn_fdot2(wO[k + 1], h1, sO1, false);
            }

            float iv = gate_eval(sI0 + sI1, -LOG2E, 1.0f, 0.0f);
            float fv = gate_eval(sF0 + sF1, -LOG2E, 1.0f, 0.0f);
            float gv = gate_eval(sG0 + sG1, -2.0f * LOG2E, 2.0f, -1.0f);
            float ov = gate_eval(sO0 + sO1, -LOG2E, 1.0f, 0.0f);

            c = fmaf(fv, c, iv * gv);
            float th = gate_eval(c, -2.0f * LOG2E, 2.0f, -1.0f); // tanh(c)
            float h = ov * th;

            // publish h, then issue next gather; DPP reduce below overlaps latency
            hbase[j] = (_Float16)h;
            hcur = gather_h(hbase);

            // fused output projection: width-32 reduce on VALU via DPP.
            // row_shr 1/2/4/8 then row_bcast15 -> total lands in lane 31 / 63.
            float po = woj * h;
            po = dpp_add<0x111>(po);
            po = dpp_add<0x112>(po);
            po = dpp_add<0x114>(po);
            po = dpp_add<0x118>(po);
            po = dpp_add<0x142>(po);
            outv[u] = po + bo0;
        }
        if ((lane & 31) == 31) {
            *(float4*)(op + t) = make_float4(outv[0], outv[1], outv[2], outv[3]);
        }
        x4 = x4n;
    }
}

extern "C" void kernel_launch(void* const* d_in, const int* in_sizes, int n_in,
                              void* d_out, int out_size, void* d_ws, size_t ws_size,
                              hipStream_t stream) {
    const float* x_seq = (const float*)d_in[0];
    const float* Wp    = (const float*)d_in[1];
    const float* bp    = (const float*)d_in[2];
    const float* W_ih  = (const float*)d_in[3];
    const float* W_hh  = (const float*)d_in[4];
    const float* b_ih  = (const float*)d_in[5];
    const float* b_hh  = (const float*)d_in[6];
    const float* Wo    = (const float*)d_in[7];
    const float* bo    = (const float*)d_in[8];
    float* out = (float*)d_out;

    dim3 grid(BB / 8);   // 4 waves/block, 2 batch elements/wave
    dim3 block(256);
    lstm_fused_kernel<<<grid, block, 0, stream>>>(
        x_seq, Wp, bp, W_ih, W_hh, b_ih, b_hh, Wo, bo, out);
}